// Round 2
// baseline (9.768 us; speedup 1.0000x reference)
//
#include <hip/hip_runtime.h>

#define GLOBAL_AVERAGE 3.5f
#define NUM_FACTORS 64

// 8 lanes per batch row. Each lane loads 2 float4 (32B) from each factor
// table -> 4 independent global loads in flight per thread. Bias loads are
// issued by ALL lanes of the group (same address -> broadcast) before the
// shuffle-reduce so they overlap with it. Width-8 shfl_xor reduce (3 steps).
__global__ __launch_bounds__(256) void bmf_predict_kernel(
    const int* __restrict__ users,
    const int* __restrict__ items,
    const float* __restrict__ user_factors,
    const float* __restrict__ item_factors,
    const float* __restrict__ user_biases,
    const float* __restrict__ item_biases,
    float* __restrict__ out,
    int batch)
{
    const int tid  = blockIdx.x * blockDim.x + threadIdx.x;
    const int row  = tid >> 3;   // 8 lanes per batch row
    const int lane = tid & 7;
    if (row >= batch) return;

    const int u  = users[row];
    const int it = items[row];

    const float4* ua = reinterpret_cast<const float4*>(
        user_factors + (size_t)u * NUM_FACTORS + lane * 8);
    const float4* ib4 = reinterpret_cast<const float4*>(
        item_factors + (size_t)it * NUM_FACTORS + lane * 8);

    // Issue all 4 factor loads + both bias loads before any use.
    const float4 a0 = ua[0];
    const float4 a1 = ua[1];
    const float4 b0 = ib4[0];
    const float4 b1 = ib4[1];
    const float ub = user_biases[u];   // broadcast within group
    const float bb = item_biases[it];

    float p = a0.x * b0.x;
    p = fmaf(a0.y, b0.y, p);
    p = fmaf(a0.z, b0.z, p);
    p = fmaf(a0.w, b0.w, p);
    p = fmaf(a1.x, b1.x, p);
    p = fmaf(a1.y, b1.y, p);
    p = fmaf(a1.z, b1.z, p);
    p = fmaf(a1.w, b1.w, p);

    // reduce across the 8 lanes of this row's group
    p += __shfl_xor(p, 1, 8);
    p += __shfl_xor(p, 2, 8);
    p += __shfl_xor(p, 4, 8);

    if (lane == 0) {
        out[row] = GLOBAL_AVERAGE + ub + bb + p;
    }
}

extern "C" void kernel_launch(void* const* d_in, const int* in_sizes, int n_in,
                              void* d_out, int out_size, void* d_ws, size_t ws_size,
                              hipStream_t stream)
{
    const int*   users        = (const int*)  d_in[0];
    const int*   items        = (const int*)  d_in[1];
    const float* user_factors = (const float*)d_in[2];
    const float* item_factors = (const float*)d_in[3];
    const float* user_biases  = (const float*)d_in[4];
    const float* item_biases  = (const float*)d_in[5];
    float* out = (float*)d_out;

    const int batch = in_sizes[0];
    const int threads_total = batch * 8;   // 8 lanes per row
    const int block = 256;
    const int grid = (threads_total + block - 1) / block;

    bmf_predict_kernel<<<grid, block, 0, stream>>>(
        users, items, user_factors, item_factors,
        user_biases, item_biases, out, batch);
}